// Round 8
// baseline (433.312 us; speedup 1.0000x reference)
//
#include <hip/hip_runtime.h>
#include <math.h>

#define D      4096
#define NPREV  8191
#define NROWS  8192
#define FB     512
#define FR     (NROWS / FB)   // 16
#define NGRP   32
#define GSZ    (FB / NGRP)    // 16
#define NCH    64             // kq chunks

typedef float f4 __attribute__((ext_vector_type(4)));

static __device__ __forceinline__ f4 nt_load4(const float* p) {
    return __builtin_nontemporal_load(reinterpret_cast<const f4*>(p));
}
static __device__ __forceinline__ void nt_store4(f4 v, float* p) {
    __builtin_nontemporal_store(v, reinterpret_cast<f4*>(p));
}
static __device__ __forceinline__ f4 ld4(const float* p) {
    return *reinterpret_cast<const f4*>(p);
}
static __device__ __forceinline__ void st4(f4 v, float* p) {
    *reinterpret_cast<f4*>(p) = v;
}

// ---- K1/K5: out[row] = dot(W[row,:], v) (+resid). 1024 blocks x 256 ---------
template<bool RESIDUAL>
__global__ void k_matvec_rows(const float* __restrict__ W, const float* __restrict__ v,
                              const float* __restrict__ resid, float* __restrict__ out) {
    int row  = blockIdx.x * 4 + (threadIdx.x >> 6);
    int lane = threadIdx.x & 63;
    const float* Wrow = W + (size_t)row * D;
    float acc = 0.f;
    #pragma unroll
    for (int i = 0; i < 16; ++i) {
        int c = lane + i * 64;
        f4 w = nt_load4(Wrow + 4 * c);
        f4 x = ld4(v + 4 * c);
        acc += w.x * x.x + w.y * x.y + w.z * x.z + w.w * x.w;
    }
    #pragma unroll
    for (int off = 32; off; off >>= 1) acc += __shfl_down(acc, off, 64);
    if (lane == 0) out[row] = RESIDUAL ? (acc + resid[row]) : acc;
}

// ---- K2: kq fused — partial + fan-in reduce. grid(4, NCH) x 256 -------------
// part[c][slice s]: sum over chunk c's 64 rows of q[m]*W[m][d].
// Last block per slice (atomic counter) reduces the 64 chunk partials.
__global__ void k_kq_fused(const float* __restrict__ W, const float* __restrict__ q,
                           float* part, float* kq, unsigned int* cnt) {
    __shared__ int s_flag;
    int t = threadIdx.x;          // 256
    int s = blockIdx.x;           // slice 0..3 (1024 f4 cols each... 256 f4)
    int c = blockIdx.y;           // chunk 0..63
    int d4 = s * 256 + t;         // f4 column
    int m0 = c * (D / NCH);
    f4 acc = (f4)0.f;
    #pragma unroll 4
    for (int r = 0; r < D / NCH; ++r)
        acc += q[m0 + r] * nt_load4(W + (size_t)(m0 + r) * D + 4 * d4);
    st4(acc, part + (size_t)c * D + 4 * d4);
    __threadfence();              // release: make partial visible device-wide
    __syncthreads();
    if (t == 0) s_flag = (atomicAdd(&cnt[s], 1u) == NCH - 1);
    __syncthreads();
    if (s_flag) {
        __threadfence();          // acquire
        f4 a = (f4)0.f;
        #pragma unroll 8
        for (int cc = 0; cc < NCH; ++cc)
            a += ld4(part + (size_t)cc * D + 4 * d4);
        st4(a, kq + 4 * d4);
    }
}

// ---- K3: register-resident flash + fan-in group combine ---------------------
__global__ __launch_bounds__(1024, 4) void k_flash(
        const float* __restrict__ prev, const float* __restrict__ inp,
        const float* __restrict__ kq, float* __restrict__ io,
        float* ms, float* ctxpart, float* ctx2, float* msg, unsigned int* cnt) {
    __shared__ float s_wred[16][FR];
    __shared__ float s_log[FR];
    __shared__ float s_gms[2 * GSZ];
    __shared__ int s_flag;
    const int bid = blockIdx.x;
    const int n0 = bid * FR;
    const int t = threadIdx.x;
    const int wid = t >> 6, lane = t & 63;
    const f4 kqv = ld4(kq + 4 * t);

    f4 x[FR];
    #pragma unroll
    for (int r = 0; r < FR; ++r) {
        int n = n0 + r;
        const float* src = (n < NPREV) ? (prev + (size_t)n * D) : inp;
        x[r] = nt_load4(src + 4 * t);
    }
    float p[FR];
    #pragma unroll
    for (int r = 0; r < FR; ++r) {
        int n = n0 + r;
        nt_store4(x[r], io + (size_t)n * D + 4 * t);
        p[r] = x[r].x * kqv.x + x[r].y * kqv.y + x[r].z * kqv.z + x[r].w * kqv.w;
    }
    #pragma unroll
    for (int r = 0; r < FR; ++r) {
        float v = p[r];
        #pragma unroll
        for (int off = 32; off; off >>= 1) v += __shfl_down(v, off, 64);
        if (lane == 0) s_wred[wid][r] = v;
    }
    __syncthreads();
    if (t < FR) {
        float s = 0.f;
        #pragma unroll
        for (int w = 0; w < 16; ++w) s += s_wred[w][t];
        s_log[t] = s;
    }
    __syncthreads();
    float m_b = -INFINITY;
    #pragma unroll
    for (int r = 0; r < FR; ++r) m_b = fmaxf(m_b, s_log[r]);
    float e[FR], s_b = 0.f;
    #pragma unroll
    for (int r = 0; r < FR; ++r) { e[r] = __expf(s_log[r] - m_b); s_b += e[r]; }
    f4 a = (f4)0.f;
    #pragma unroll
    for (int r = 0; r < FR; ++r) a += e[r] * x[r];
    st4(a, ctxpart + (size_t)bid * D + 4 * t);
    if (t == 0) { ms[2 * bid] = m_b; ms[2 * bid + 1] = s_b; }

    // ---- fan-in: last block of each 16-block group combines its group ----
    const int g = bid / GSZ;
    __threadfence();              // release ctxpart + ms
    __syncthreads();
    if (t == 0) s_flag = (atomicAdd(&cnt[g], 1u) == GSZ - 1);
    __syncthreads();
    if (s_flag) {
        __threadfence();          // acquire
        if (t < 2 * GSZ) s_gms[t] = ms[2 * GSZ * g + t];
        __syncthreads();
        float Mg = -INFINITY;
        #pragma unroll
        for (int i = 0; i < GSZ; ++i) Mg = fmaxf(Mg, s_gms[2 * i]);
        float Sg = 0.f;
        #pragma unroll
        for (int i = 0; i < GSZ; ++i) Sg += s_gms[2 * i + 1] * __expf(s_gms[2 * i] - Mg);
        f4 ga = (f4)0.f;
        #pragma unroll
        for (int i = 0; i < GSZ; ++i) {
            int b = GSZ * g + i;
            ga += __expf(s_gms[2 * i] - Mg) * ld4(ctxpart + (size_t)b * D + 4 * t);
        }
        st4(ga, ctx2 + (size_t)g * D + 4 * t);
        if (t == 0) { msg[2 * g] = Mg; msg[2 * g + 1] = Sg; }
    }
}

// ---- K4: merge 32 groups, normalize. grid(4) x 256 --------------------------
__global__ void k_combine2(const float* __restrict__ msg, const float* __restrict__ ctx2,
                           float* __restrict__ ctx) {
    __shared__ float sm[2 * NGRP];
    int t = threadIdx.x;
    if (t < 2 * NGRP) sm[t] = msg[t];
    __syncthreads();
    float M = -INFINITY;
    #pragma unroll
    for (int g = 0; g < NGRP; ++g) M = fmaxf(M, sm[2 * g]);
    float S = 0.f;
    #pragma unroll
    for (int g = 0; g < NGRP; ++g) S += sm[2 * g + 1] * __expf(sm[2 * g] - M);
    int d4 = blockIdx.x * 256 + t;
    f4 a = (f4)0.f;
    #pragma unroll
    for (int g = 0; g < NGRP; ++g)
        a += __expf(sm[2 * g] - M) * ld4(ctx2 + (size_t)g * D + 4 * d4);
    st4(a * (1.f / S), ctx + 4 * d4);
}

extern "C" void kernel_launch(void* const* d_in, const int* in_sizes, int n_in,
                              void* d_out, int out_size, void* d_ws, size_t ws_size,
                              hipStream_t stream) {
    const float* prev = (const float*)d_in[0];   // (8191, 4096)
    const float* inp  = (const float*)d_in[1];   // (4096,)
    const float* W_Q  = (const float*)d_in[2];
    const float* W_K  = (const float*)d_in[3];
    const float* W_V  = (const float*)d_in[4];
    float* out = (float*)d_out;                  // [0:4096]=output, [4096:]=inputs
    float* io  = out + D;
    float* ws  = (float*)d_ws;

    // ws: q D | kq D | part NCH*D | ms 2*FB | ctxpart FB*D | ctx2 NGRP*D |
    //     msg 2*NGRP | ctx D | counters (4 + 32 u32)   (~9.9 MB)
    float* q       = ws;
    float* kq      = q + D;
    float* part    = kq + D;
    float* ms      = part + (size_t)NCH * D;
    float* ctxpart = ms + 2 * FB;
    float* ctx2    = ctxpart + (size_t)FB * D;
    float* msg     = ctx2 + (size_t)NGRP * D;
    float* ctx     = msg + 2 * NGRP;
    unsigned int* cnt_kq    = (unsigned int*)(ctx + D);
    unsigned int* cnt_flash = cnt_kq + 4;

    // zero the fan-in counters every call (graph-captured, replay-safe)
    hipMemsetAsync(cnt_kq, 0, (4 + NGRP) * sizeof(unsigned int), stream);

    k_matvec_rows<false><<<1024, 256, 0, stream>>>(W_Q, inp, nullptr, q);
    k_kq_fused<<<dim3(4, NCH), 256, 0, stream>>>(W_K, q, part, kq, cnt_kq);
    k_flash<<<FB, 1024, 0, stream>>>(prev, inp, kq, io, ms, ctxpart, ctx2, msg, cnt_flash);
    k_combine2<<<4, 256, 0, stream>>>(msg, ctx2, ctx);
    k_matvec_rows<true><<<1024, 256, 0, stream>>>(W_V, ctx, inp, out);
}

// Round 9
// 115.976 us; speedup vs baseline: 3.7362x; 3.7362x over previous
//
#include <hip/hip_runtime.h>
#include <math.h>

#define D      4096
#define NPREV  8191
#define NROWS  8192
#define FB     512
#define FR     (NROWS / FB)   // 16

typedef float f4 __attribute__((ext_vector_type(4)));

static __device__ __forceinline__ f4 nt_load4(const float* p) {
    return __builtin_nontemporal_load(reinterpret_cast<const f4*>(p));
}
static __device__ __forceinline__ void nt_store4(f4 v, float* p) {
    __builtin_nontemporal_store(v, reinterpret_cast<f4*>(p));
}
static __device__ __forceinline__ f4 ld4(const float* p) {
    return *reinterpret_cast<const f4*>(p);
}
static __device__ __forceinline__ void st4(f4 v, float* p) {
    *reinterpret_cast<f4*>(p) = v;
}

// ---- K1/K5: out[row] = dot(W[row,:], v) (+resid). 1024 blocks x 256 ---------
template<bool RESIDUAL>
__global__ void k_matvec_rows(const float* __restrict__ W, const float* __restrict__ v,
                              const float* __restrict__ resid, float* __restrict__ out) {
    int row  = blockIdx.x * 4 + (threadIdx.x >> 6);
    int lane = threadIdx.x & 63;
    const float* Wrow = W + (size_t)row * D;
    float acc = 0.f;
    #pragma unroll
    for (int i = 0; i < 16; ++i) {
        int c = lane + i * 64;
        f4 w = nt_load4(Wrow + 4 * c);
        f4 x = ld4(v + 4 * c);
        acc += w.x * x.x + w.y * x.y + w.z * x.z + w.w * x.w;
    }
    #pragma unroll
    for (int off = 32; off; off >>= 1) acc += __shfl_down(acc, off, 64);
    if (lane == 0) out[row] = RESIDUAL ? (acc + resid[row]) : acc;
}

// ---- K2: kq[d] = sum_m q[m] * W_K[m][d], single kernel. 256 blocks x 256 ----
// Block b owns 4 f4 columns (64B strip) of every row; q staged in LDS.
__global__ void k_kq(const float* __restrict__ W, const float* __restrict__ q,
                     float* __restrict__ kq) {
    __shared__ float s_q[D];            // 16 KB
    __shared__ f4 s_part[64][4];        // 4 KB
    int t = threadIdx.x;
    int b = blockIdx.x;
    for (int i = t; i < D; i += 256) s_q[i] = q[i];
    __syncthreads();
    int c4 = b * 4 + (t & 3);           // f4 column
    int r0 = t >> 2;                    // 0..63
    f4 acc = (f4)0.f;
    #pragma unroll 16
    for (int i = 0; i < 64; ++i) {
        int m = r0 + i * 64;
        acc += s_q[m] * nt_load4(W + (size_t)m * D + 4 * c4);
    }
    s_part[r0][t & 3] = acc;
    __syncthreads();
    if (t < 4) {
        f4 a = (f4)0.f;
        #pragma unroll
        for (int g = 0; g < 64; ++g) a += s_part[g][t];
        st4(a, kq + 4 * (b * 4 + t));
    }
}

// ---- K3: register-resident flash (R7-proven, no fan-in). FB=512 x 1024 ------
__global__ __launch_bounds__(1024, 4) void k_flash(
        const float* __restrict__ prev, const float* __restrict__ inp,
        const float* __restrict__ kq, float* __restrict__ io,
        float* __restrict__ ms, float* __restrict__ ctxpart) {
    __shared__ float s_wred[16][FR];
    __shared__ float s_log[FR];
    const int n0 = blockIdx.x * FR;
    const int t = threadIdx.x;
    const int wid = t >> 6, lane = t & 63;
    const f4 kqv = ld4(kq + 4 * t);

    f4 x[FR];
    #pragma unroll
    for (int r = 0; r < FR; ++r) {
        int n = n0 + r;
        const float* src = (n < NPREV) ? (prev + (size_t)n * D) : inp;
        x[r] = ld4(src + 4 * t);        // regular load: let L3 retain prev
    }
    float p[FR];
    #pragma unroll
    for (int r = 0; r < FR; ++r) {
        int n = n0 + r;
        nt_store4(x[r], io + (size_t)n * D + 4 * t);
        p[r] = x[r].x * kqv.x + x[r].y * kqv.y + x[r].z * kqv.z + x[r].w * kqv.w;
    }
    #pragma unroll
    for (int r = 0; r < FR; ++r) {
        float v = p[r];
        #pragma unroll
        for (int off = 32; off; off >>= 1) v += __shfl_down(v, off, 64);
        if (lane == 0) s_wred[wid][r] = v;
    }
    __syncthreads();
    if (t < FR) {
        float s = 0.f;
        #pragma unroll
        for (int w = 0; w < 16; ++w) s += s_wred[w][t];
        s_log[t] = s;
    }
    __syncthreads();
    float m_b = -INFINITY;
    #pragma unroll
    for (int r = 0; r < FR; ++r) m_b = fmaxf(m_b, s_log[r]);
    float e[FR], s_b = 0.f;
    #pragma unroll
    for (int r = 0; r < FR; ++r) { e[r] = __expf(s_log[r] - m_b); s_b += e[r]; }
    f4 a = (f4)0.f;
    #pragma unroll
    for (int r = 0; r < FR; ++r) a += e[r] * x[r];
    st4(a, ctxpart + (size_t)blockIdx.x * D + 4 * t);
    if (t == 0) { ms[2 * blockIdx.x] = m_b; ms[2 * blockIdx.x + 1] = s_b; }
}

// ---- K4: single-stage combine of all 512 partials. 32 blocks x 256 ----------
__global__ void k_combine(const float* __restrict__ ms, const float* __restrict__ ctxpart,
                          float* __restrict__ ctx) {
    __shared__ float s_w[FB];           // exp weights
    __shared__ float s_red[12];
    __shared__ f4 s_acc[8][32];
    int t = threadIdx.x;                // 256
    int lane = t & 63, wid = t >> 6;
    // global max M over 512 block maxes (each thread covers 2)
    float m0 = ms[2 * t], m1 = ms[2 * (t + 256)];
    float mx = fmaxf(m0, m1);
    #pragma unroll
    for (int off = 32; off; off >>= 1) mx = fmaxf(mx, __shfl_down(mx, off, 64));
    if (lane == 0) s_red[wid] = mx;
    __syncthreads();
    float M = fmaxf(fmaxf(s_red[0], s_red[1]), fmaxf(s_red[2], s_red[3]));
    // weights + global sum S
    float w0 = __expf(m0 - M), w1 = __expf(m1 - M);
    s_w[t] = w0; s_w[t + 256] = w1;
    float sc = w0 * ms[2 * t + 1] + w1 * ms[2 * (t + 256) + 1];
    #pragma unroll
    for (int off = 32; off; off >>= 1) sc += __shfl_down(sc, off, 64);
    if (lane == 0) s_red[8 + wid] = sc;
    __syncthreads();
    float S = s_red[8] + s_red[9] + s_red[10] + s_red[11];
    // weighted sum of 512 partial slices for this block's 32 f4 columns
    int c  = t & 31;                    // col within block
    int g8 = t >> 5;                    // 0..7: which 64-partial span
    int col4 = blockIdx.x * 32 + c;
    f4 a = (f4)0.f;
    #pragma unroll 8
    for (int i = 0; i < 64; ++i) {
        int p = g8 * 64 + i;
        a += s_w[p] * ld4(ctxpart + (size_t)p * D + 4 * col4);
    }
    s_acc[g8][c] = a;
    __syncthreads();
    if (t < 32) {
        f4 aa = (f4)0.f;
        #pragma unroll
        for (int g = 0; g < 8; ++g) aa += s_acc[g][t];
        st4(aa * (1.f / S), ctx + 4 * (blockIdx.x * 32 + t));
    }
}

extern "C" void kernel_launch(void* const* d_in, const int* in_sizes, int n_in,
                              void* d_out, int out_size, void* d_ws, size_t ws_size,
                              hipStream_t stream) {
    const float* prev = (const float*)d_in[0];   // (8191, 4096)
    const float* inp  = (const float*)d_in[1];   // (4096,)
    const float* W_Q  = (const float*)d_in[2];
    const float* W_K  = (const float*)d_in[3];
    const float* W_V  = (const float*)d_in[4];
    float* out = (float*)d_out;                  // [0:4096]=output, [4096:]=inputs
    float* io  = out + D;
    float* ws  = (float*)d_ws;

    // ws: q D | kq D | ms 2*FB | ctxpart FB*D | ctx D   (~8.4 MB)
    float* q       = ws;
    float* kq      = q + D;
    float* ms      = kq + D;
    float* ctxpart = ms + 2 * FB;
    float* ctx     = ctxpart + (size_t)FB * D;

    k_matvec_rows<false><<<1024, 256, 0, stream>>>(W_Q, inp, nullptr, q);
    k_kq<<<256, 256, 0, stream>>>(W_K, q, kq);
    k_flash<<<FB, 1024, 0, stream>>>(prev, inp, kq, io, ms, ctxpart);
    k_combine<<<32, 256, 0, stream>>>(ms, ctxpart, ctx);
    k_matvec_rows<true><<<1024, 256, 0, stream>>>(W_V, ctx, inp, out);
}

// Round 10
// 112.491 us; speedup vs baseline: 3.8520x; 1.0310x over previous
//
#include <hip/hip_runtime.h>
#include <math.h>

#define D      4096
#define NPREV  8191
#define NROWS  8192

typedef float f4 __attribute__((ext_vector_type(4)));

static __device__ __forceinline__ f4 nt_load4(const float* p) {
    return __builtin_nontemporal_load(reinterpret_cast<const f4*>(p));
}
static __device__ __forceinline__ void nt_store4(f4 v, float* p) {
    __builtin_nontemporal_store(v, reinterpret_cast<f4*>(p));
}
static __device__ __forceinline__ f4 ld4(const float* p) {
    return *reinterpret_cast<const f4*>(p);
}
static __device__ __forceinline__ void st4(f4 v, float* p) {
    *reinterpret_cast<f4*>(p) = v;
}

// ---- K1/K5: out[row] = dot(W[row,:], v) (+resid). 1024 blocks x 256 ---------
template<bool RESIDUAL>
__global__ void k_matvec_rows(const float* __restrict__ W, const float* __restrict__ v,
                              const float* __restrict__ resid, float* __restrict__ out) {
    int row  = blockIdx.x * 4 + (threadIdx.x >> 6);
    int lane = threadIdx.x & 63;
    const float* Wrow = W + (size_t)row * D;
    float acc = 0.f;
    #pragma unroll
    for (int i = 0; i < 16; ++i) {
        int c = lane + i * 64;
        f4 w = nt_load4(Wrow + 4 * c);
        f4 x = ld4(v + 4 * c);
        acc += w.x * x.x + w.y * x.y + w.z * x.z + w.w * x.w;
    }
    #pragma unroll
    for (int off = 32; off; off >>= 1) acc += __shfl_down(acc, off, 64);
    if (lane == 0) out[row] = RESIDUAL ? (acc + resid[row]) : acc;
}

// ---- K2: kq[d] = sum_m q[m] * W_K[m][d], single kernel. 256 blocks x 256 ----
__global__ void k_kq(const float* __restrict__ W, const float* __restrict__ q,
                     float* __restrict__ kq) {
    __shared__ float s_q[D];            // 16 KB
    __shared__ f4 s_part[64][4];        // 4 KB
    int t = threadIdx.x;
    int b = blockIdx.x;
    for (int i = t; i < D; i += 256) s_q[i] = q[i];
    __syncthreads();
    int c4 = b * 4 + (t & 3);           // f4 column
    int r0 = t >> 2;                    // 0..63
    f4 acc = (f4)0.f;
    #pragma unroll 16
    for (int i = 0; i < 64; ++i) {
        int m = r0 + i * 64;
        acc += s_q[m] * nt_load4(W + (size_t)m * D + 4 * c4);
    }
    s_part[r0][t & 3] = acc;
    __syncthreads();
    if (t < 4) {
        f4 a = (f4)0.f;
        #pragma unroll
        for (int g = 0; g < 64; ++g) a += s_part[g][t];
        st4(a, kq + 4 * (b * 4 + t));
    }
}

// ---- K3 main: LDS-resident flash. FB=2048 x 1024 thr, FR=4 rows/block ------
// Thread t owns f4 column t. Row tile parked in LDS (not VGPRs) so the
// memory pipeline keeps full MLP and the post-softmax pass re-reads LDS.
#define FBL  2048
#define FRL  4
__global__ __launch_bounds__(1024, 8) void k_flash_lds(
        const float* __restrict__ prev, const float* __restrict__ inp,
        const float* __restrict__ kq, float* __restrict__ io,
        float* __restrict__ ms, float* __restrict__ ctxpart) {
    __shared__ f4 s_x[FRL][1024];       // 64 KB
    __shared__ float s_wred[16][FRL];
    __shared__ float s_log[FRL];
    const int n0 = blockIdx.x * FRL;
    const int t = threadIdx.x;
    const int wid = t >> 6, lane = t & 63;
    const f4 kqv = ld4(kq + 4 * t);

    f4 x[FRL];
    #pragma unroll
    for (int r = 0; r < FRL; ++r) {     // 4 independent loads: full MLP
        int n = n0 + r;
        const float* src = (n < NPREV) ? (prev + (size_t)n * D) : inp;
        x[r] = ld4(src + 4 * t);
    }
    float p[FRL];
    #pragma unroll
    for (int r = 0; r < FRL; ++r) {
        int n = n0 + r;
        nt_store4(x[r], io + (size_t)n * D + 4 * t);
        s_x[r][t] = x[r];
        p[r] = x[r].x * kqv.x + x[r].y * kqv.y + x[r].z * kqv.z + x[r].w * kqv.w;
    }
    #pragma unroll
    for (int r = 0; r < FRL; ++r) {
        float v = p[r];
        #pragma unroll
        for (int off = 32; off; off >>= 1) v += __shfl_down(v, off, 64);
        if (lane == 0) s_wred[wid][r] = v;
    }
    __syncthreads();
    if (t < FRL) {
        float s = 0.f;
        #pragma unroll
        for (int w = 0; w < 16; ++w) s += s_wred[w][t];
        s_log[t] = s;
    }
    __syncthreads();
    float m_b = -INFINITY;
    #pragma unroll
    for (int r = 0; r < FRL; ++r) m_b = fmaxf(m_b, s_log[r]);
    float e[FRL], s_b = 0.f;
    #pragma unroll
    for (int r = 0; r < FRL; ++r) { e[r] = __expf(s_log[r] - m_b); s_b += e[r]; }
    f4 a = (f4)0.f;
    #pragma unroll
    for (int r = 0; r < FRL; ++r) a += e[r] * s_x[r][t];   // LDS re-read
    st4(a, ctxpart + (size_t)blockIdx.x * D + 4 * t);
    if (t == 0) { ms[2 * blockIdx.x] = m_b; ms[2 * blockIdx.x + 1] = s_b; }
}

// ---- K3 fallback: R9 register flash. FB=512 x 1024 --------------------------
#define FBR  512
#define FRR  16
__global__ __launch_bounds__(1024, 4) void k_flash_reg(
        const float* __restrict__ prev, const float* __restrict__ inp,
        const float* __restrict__ kq, float* __restrict__ io,
        float* __restrict__ ms, float* __restrict__ ctxpart) {
    __shared__ float s_wred[16][FRR];
    __shared__ float s_log[FRR];
    const int n0 = blockIdx.x * FRR;
    const int t = threadIdx.x;
    const int wid = t >> 6, lane = t & 63;
    const f4 kqv = ld4(kq + 4 * t);
    f4 x[FRR];
    #pragma unroll
    for (int r = 0; r < FRR; ++r) {
        int n = n0 + r;
        const float* src = (n < NPREV) ? (prev + (size_t)n * D) : inp;
        x[r] = ld4(src + 4 * t);
    }
    float p[FRR];
    #pragma unroll
    for (int r = 0; r < FRR; ++r) {
        int n = n0 + r;
        nt_store4(x[r], io + (size_t)n * D + 4 * t);
        p[r] = x[r].x * kqv.x + x[r].y * kqv.y + x[r].z * kqv.z + x[r].w * kqv.w;
    }
    #pragma unroll
    for (int r = 0; r < FRR; ++r) {
        float v = p[r];
        #pragma unroll
        for (int off = 32; off; off >>= 1) v += __shfl_down(v, off, 64);
        if (lane == 0) s_wred[wid][r] = v;
    }
    __syncthreads();
    if (t < FRR) {
        float s = 0.f;
        #pragma unroll
        for (int w = 0; w < 16; ++w) s += s_wred[w][t];
        s_log[t] = s;
    }
    __syncthreads();
    float m_b = -INFINITY;
    #pragma unroll
    for (int r = 0; r < FRR; ++r) m_b = fmaxf(m_b, s_log[r]);
    float e[FRR], s_b = 0.f;
    #pragma unroll
    for (int r = 0; r < FRR; ++r) { e[r] = __expf(s_log[r] - m_b); s_b += e[r]; }
    f4 a = (f4)0.f;
    #pragma unroll
    for (int r = 0; r < FRR; ++r) a += e[r] * x[r];
    st4(a, ctxpart + (size_t)blockIdx.x * D + 4 * t);
    if (t == 0) { ms[2 * blockIdx.x] = m_b; ms[2 * blockIdx.x + 1] = s_b; }
}

// ---- K4: combine FBT partials -> normalized ctx. 64 blocks x 256 ------------
template<int FBT>
__global__ void k_combine(const float* __restrict__ ms, const float* __restrict__ ctxpart,
                          float* __restrict__ ctx) {
    constexpr int PPT = FBT / 256;      // ms pairs per thread
    constexpr int PPG = FBT / 16;       // partials per group-thread
    __shared__ float s_w[FBT];
    __shared__ float s_red[8];
    __shared__ f4 s_acc[16][16];
    int t = threadIdx.x;                // 256
    int lane = t & 63, wid = t >> 6;
    float mloc[PPT];
    float mx = -INFINITY;
    #pragma unroll
    for (int k = 0; k < PPT; ++k) { mloc[k] = ms[2 * (t + 256 * k)]; mx = fmaxf(mx, mloc[k]); }
    #pragma unroll
    for (int off = 32; off; off >>= 1) mx = fmaxf(mx, __shfl_down(mx, off, 64));
    if (lane == 0) s_red[wid] = mx;
    __syncthreads();
    float M = fmaxf(fmaxf(s_red[0], s_red[1]), fmaxf(s_red[2], s_red[3]));
    float sc = 0.f;
    #pragma unroll
    for (int k = 0; k < PPT; ++k) {
        float w = __expf(mloc[k] - M);
        s_w[t + 256 * k] = w;
        sc += w * ms[2 * (t + 256 * k) + 1];
    }
    #pragma unroll
    for (int off = 32; off; off >>= 1) sc += __shfl_down(sc, off, 64);
    if (lane == 0) s_red[4 + wid] = sc;
    __syncthreads();
    float S = s_red[4] + s_red[5] + s_red[6] + s_red[7];
    int c = t & 15, g = t >> 4;
    int col4 = blockIdx.x * 16 + c;
    f4 a = (f4)0.f;
    #pragma unroll 8
    for (int i = 0; i < PPG; ++i) {
        int pp = g * PPG + i;
        a += s_w[pp] * ld4(ctxpart + (size_t)pp * D + 4 * col4);
    }
    s_acc[g][c] = a;
    __syncthreads();
    if (t < 16) {
        f4 aa = (f4)0.f;
        #pragma unroll
        for (int gg = 0; gg < 16; ++gg) aa += s_acc[gg][t];
        st4(aa * (1.f / S), ctx + 4 * (blockIdx.x * 16 + t));
    }
}

extern "C" void kernel_launch(void* const* d_in, const int* in_sizes, int n_in,
                              void* d_out, int out_size, void* d_ws, size_t ws_size,
                              hipStream_t stream) {
    const float* prev = (const float*)d_in[0];   // (8191, 4096)
    const float* inp  = (const float*)d_in[1];   // (4096,)
    const float* W_Q  = (const float*)d_in[2];
    const float* W_K  = (const float*)d_in[3];
    const float* W_V  = (const float*)d_in[4];
    float* out = (float*)d_out;                  // [0:4096]=output, [4096:]=inputs
    float* io  = out + D;
    float* ws  = (float*)d_ws;

    // main ws: q D | kq D | ms 2*FBL | ctxpart FBL*D | ctx D  (~33.6 MB)
    size_t need_main = (size_t)(2 * D + 2 * FBL + (size_t)FBL * D + D) * sizeof(float);

    float* q  = ws;
    float* kq = q + D;
    float* ms = kq + D;

    if (ws_size >= need_main) {
        float* ctxpart = ms + 2 * FBL;
        float* ctx     = ctxpart + (size_t)FBL * D;
        k_matvec_rows<false><<<1024, 256, 0, stream>>>(W_Q, inp, nullptr, q);
        k_kq<<<256, 256, 0, stream>>>(W_K, q, kq);
        k_flash_lds<<<FBL, 1024, 0, stream>>>(prev, inp, kq, io, ms, ctxpart);
        k_combine<FBL><<<64, 256, 0, stream>>>(ms, ctxpart, ctx);
        k_matvec_rows<true><<<1024, 256, 0, stream>>>(W_V, ctx, inp, out);
    } else {
        // fallback: R9-proven register flash (~8.4 MB ws)
        float* ctxpart = ms + 2 * FBR;
        float* ctx     = ctxpart + (size_t)FBR * D;
        k_matvec_rows<false><<<1024, 256, 0, stream>>>(W_Q, inp, nullptr, q);
        k_kq<<<256, 256, 0, stream>>>(W_K, q, kq);
        k_flash_reg<<<FBR, 1024, 0, stream>>>(prev, inp, kq, io, ms, ctxpart);
        k_combine<FBR><<<64, 256, 0, stream>>>(ms, ctxpart, ctx);
        k_matvec_rows<true><<<1024, 256, 0, stream>>>(W_V, ctx, inp, out);
    }
}